// Round 9
// baseline (262.635 us; speedup 1.0000x reference)
//
#include <hip/hip_runtime.h>

// ---------------------------------------------------------------------------
// SelfAttention: out = softmax((x@Wk+bk) @ (x@Wq+bq)^T) @ (x@Wv+bv)
// B=4, N=2048, E=A=1024, fp32 in/out.
// R17: scores GEMM re-tiled TM=128 x TN=64 (2048 blocks, 24KB LDS -> 6/CU;
// was 128x128, 1024 blocks = 4/CU = 537 TF vs proj's 830 at 6/CU).
//  - mode-1 epilogue: block == one 64-col slice; two-phase LDS combine
//    (32-col maxes -> slice max M -> P~=exp(s-M) + sums -> part). M is
//    bit-identical to the old 64-col max; pv semantics unchanged.
//  - MODE is now a template param (proj codegen untouched);
//    scores_vT pinned at __launch_bounds__(256,6) (VGPR 64 already achieved).
//  - prep / proj / pv_fused unchanged from R16.
// ---------------------------------------------------------------------------

typedef __attribute__((ext_vector_type(8))) _Float16 half8;   // 4 VGPRs
typedef __attribute__((ext_vector_type(4))) float floatx4;

#define BK 64
#define MFMA16 __builtin_amdgcn_mfma_f32_16x16x32_f16

static __device__ __forceinline__ unsigned short f2h(float f) {
    _Float16 h = (_Float16)f;          // RNE
    return *(unsigned short*)&h;
}
static __device__ __forceinline__ float h2f(unsigned short u) {
    _Float16 h = *(_Float16*)&u;
    return (float)h;
}

// async global->LDS, 16B per lane; LDS dst = wave-uniform base + lane*16
static __device__ __forceinline__ void gll16(const unsigned short* g,
                                             unsigned short* l) {
    __builtin_amdgcn_global_load_lds(
        (__attribute__((address_space(1))) void*)(g),
        (__attribute__((address_space(3))) void*)(l), 16, 0, 0);
}

// XCD-chunked bijective remap (m157; requires nwg % 8 == 0).
static __device__ __forceinline__ void xcd_remap(int& bx, int& by, int& bz) {
    const int gx = gridDim.x, gy = gridDim.y, gz = gridDim.z;
    const int flat = blockIdx.x + gx * (blockIdx.y + gy * blockIdx.z);
    const int w = (flat & 7) * ((gx * gy * gz) >> 3) + (flat >> 3);
    bx = w % gx;
    const int r = w / gx;
    by = r % gy;
    bz = r / gy;
}

// ---------------------------------------------------------------------------
// prep: blocks 0..8191 cast x -> fp16;
//       8192..8959: 64x64 W-transpose tiles (256 per W, 3 Ws) -> WT fp16;
//       8960..8971: bias concat (12 blocks x 256 = 3072).
// ---------------------------------------------------------------------------
__global__ __launch_bounds__(256)
void prep(const float* __restrict__ x,
          const float* __restrict__ W0, const float* __restrict__ W1,
          const float* __restrict__ W2,
          const float* __restrict__ b0, const float* __restrict__ b1,
          const float* __restrict__ b2,
          unsigned short* __restrict__ x16, unsigned short* __restrict__ WT,
          float* __restrict__ bias3) {
    __shared__ unsigned short wtile[64][76];   // pad 76: 152B row, 8B-aligned
    const int bid = blockIdx.x;
    const int tid = threadIdx.x;
    if (bid < 8192) {
        int i = bid * 1024 + tid * 4;
        float4 f = *(const float4*)(x + i);
        *(ushort4*)(x16 + i) =
            make_ushort4(f2h(f.x), f2h(f.y), f2h(f.z), f2h(f.w));
    } else if (bid < 8960) {
        int wz = bid - 8192;
        int z = wz >> 8;                     // which W (256 tiles each)
        int t = wz & 255;
        const float* W = z == 0 ? W0 : (z == 1 ? W1 : W2);
        unsigned short* Tz = WT + (size_t)z * 1024 * 1024;
        int c0 = (t & 15) * 64, r0 = (t >> 4) * 64;
        int tx = tid & 15, ty = tid >> 4;
#pragma unroll
        for (int j = 0; j < 4; ++j) {
            int r = ty + j * 16;
            float4 f = *(const float4*)(W + (r0 + r) * 1024 + c0 + tx * 4);
            *(ushort4*)&wtile[r][tx * 4] =
                make_ushort4(f2h(f.x), f2h(f.y), f2h(f.z), f2h(f.w));
        }
        __syncthreads();
#pragma unroll
        for (int j = 0; j < 4; ++j) {
            int a = ty + j * 16;
            ushort4 u = make_ushort4(wtile[tx * 4 + 0][a], wtile[tx * 4 + 1][a],
                                     wtile[tx * 4 + 2][a], wtile[tx * 4 + 3][a]);
            *(ushort4*)(Tz + (size_t)(c0 + a) * 1024 + r0 + tx * 4) = u;
        }
    } else {
        int i = (bid - 8960) * 256 + tid;    // 12*256 = 3072
        int s = i >> 10;
        const float* b = s == 0 ? b0 : (s == 1 ? b1 : b2);
        bias3[i] = b[i & 1023];
    }
}

// ---------------------------------------------------------------------------
// NT GEMM body (R11 structure, 2-barrier single-buffer):
// C[M,N] = A[M,K]*B[N,K]^T; fp16 in, fp32 acc.  Block TM x TN, 256 thr
// (4 waves 2x2; wave tile TM/2 x TN/2), BK=64.  LDS: unpadded [row][64],
// XOR chunk swizzle (pos p of row r holds chunk p ^ (r&7)) — conflict-free.
// MODE 1 (requires TN==64): softmax-prep epilogue, block == one 64-col
//   slice: two-phase LDS combine -> P~ = fp16(exp(s - sliceM)) -> Ch,
//   part[row][slice] = (sliceM, sumexp).
// MODE 2: fp16 segmented (+bias) -> Ch (k|q|v contiguous).
// ---------------------------------------------------------------------------
template <int TM, int TN, int MODE>
static __device__ __forceinline__ void gemm_body(
    unsigned short* smem, int bx, int by, int bz,
    const unsigned short* __restrict__ A,
    const unsigned short* __restrict__ B,
    const float* __restrict__ bias,
    unsigned short* __restrict__ Ch, float2* __restrict__ part,
    int N, int K, long long sA, long long sB, long long sC) {
    constexpr int WM = TM / 2;       // wave tile rows
    constexpr int MI = WM / 16;      // acc row-tiles per wave
    constexpr int WN = TN / 2;
    constexpr int NI = WN / 16;      // acc col-tiles per wave
    unsigned short* As = smem;                  // TM x BK
    unsigned short* Bs = smem + TM * BK;        // TN x BK

    const int tid = threadIdx.x;
    const int lane = tid & 63;
    const int wave = tid >> 6;          // 0..3
    const int quad = lane >> 4;
    const int l15 = lane & 15;
    const int wm = (wave & 1) * WM;
    const int wn = (wave >> 1) * WN;

    const long long zA = (long long)bz * sA;
    const long long zB = (long long)bz * sB;
    const long long zC = (long long)bz * sC;
    const int m0 = by * TM;
    const int n0 = bx * TN;

    // staging: lane i covers row i>>3; position p=i&7 gets chunk p ^ (row&7)
    const int arow = wave * (TM / 4) + (lane >> 3);
    const int brow = wave * (TN / 4) + (lane >> 3);
    const int schunk8 = (((lane & 7) ^ ((lane >> 3) & 7)) << 3);
    const long long aoff = zA + (long long)(m0 + arow) * K + schunk8;
    const long long boff = zB + (long long)(n0 + brow) * K + schunk8;
    unsigned short* lA = As + (wave * (TM / 4)) * BK;
    unsigned short* lB = Bs + (wave * (TN / 4)) * BK;

    floatx4 zero = {0.f, 0.f, 0.f, 0.f};
    floatx4 acc[MI][NI];
#pragma unroll
    for (int i = 0; i < MI; ++i)
#pragma unroll
        for (int j = 0; j < NI; ++j) acc[i][j] = zero;

    for (int k0 = 0; k0 < K; k0 += BK) {
        __syncthreads();
#pragma unroll
        for (int j = 0; j < TM / 32; ++j)
            gll16(A + aoff + k0 + (long long)j * 8 * K, lA + j * 8 * BK);
#pragma unroll
        for (int j = 0; j < TN / 32; ++j)
            gll16(B + boff + k0 + (long long)j * 8 * K, lB + j * 8 * BK);
        __syncthreads();

#pragma unroll
        for (int t = 0; t < 2; ++t) {      // two K=32 MFMA steps per BK=64
            half8 a[MI], b[NI];
#pragma unroll
            for (int mi = 0; mi < MI; ++mi) {
                int r = wm + mi * 16 + l15;
                int p = (t * 4 + quad) ^ (r & 7);
                a[mi] = *(const half8*)&As[r * BK + p * 8];
            }
#pragma unroll
            for (int ni = 0; ni < NI; ++ni) {
                int r = wn + ni * 16 + l15;
                int p = (t * 4 + quad) ^ (r & 7);
                b[ni] = *(const half8*)&Bs[r * BK + p * 8];
            }
#pragma unroll
            for (int mi = 0; mi < MI; ++mi)
#pragma unroll
                for (int ni = 0; ni < NI; ++ni)
                    acc[mi][ni] = MFMA16(a[mi], b[ni], acc[mi][ni], 0, 0, 0);
        }
    }

    // epilogue: C/D layout col=lane&15, row=quad*4+reg  [verified m89/m91]
    if constexpr (MODE == 1) {
        // TN==64: block spans exactly slice bx.  Cross-wave combine via LDS
        // (reuse As; barrier first so last tile's ds_reads are all done).
        __syncthreads();
        float* bufm = (float*)smem;            // [TM][2]
        float* bufs = bufm + TM * 2;           // [TM][2]
        const int half = wn >> 5;              // 0|1
        // phase 1: 32-col max per row-half
#pragma unroll
        for (int mi = 0; mi < MI; ++mi)
#pragma unroll
            for (int r = 0; r < 4; ++r) {
                float mx = acc[mi][0][r];
#pragma unroll
                for (int ni = 1; ni < NI; ++ni)
                    mx = fmaxf(mx, acc[mi][ni][r]);
#pragma unroll
                for (int off = 1; off <= 8; off <<= 1)
                    mx = fmaxf(mx, __shfl_xor(mx, off));
                if (l15 == 0)
                    bufm[(wm + mi * 16 + quad * 4 + r) * 2 + half] = mx;
            }
        __syncthreads();
        // phase 2: slice max -> write P~, accumulate 32-col sums
#pragma unroll
        for (int mi = 0; mi < MI; ++mi)
#pragma unroll
            for (int r = 0; r < 4; ++r) {
                const int rowl = wm + mi * 16 + quad * 4 + r;
                const float M = fmaxf(bufm[rowl * 2], bufm[rowl * 2 + 1]);
                float sm = 0.f;
#pragma unroll
                for (int ni = 0; ni < NI; ++ni) {
                    float e = __expf(acc[mi][ni][r] - M);
                    sm += e;
                    Ch[zC + (long long)(m0 + rowl) * N + n0 + wn + ni * 16 +
                       l15] = f2h(e);
                }
#pragma unroll
                for (int off = 1; off <= 8; off <<= 1)
                    sm += __shfl_xor(sm, off);
                if (l15 == 0) bufs[rowl * 2 + half] = sm;
            }
        __syncthreads();
        // phase 3: one thread per row writes (M, S)
        if (tid < TM) {
            const float M = fmaxf(bufm[tid * 2], bufm[tid * 2 + 1]);
            const float S = bufs[tid * 2] + bufs[tid * 2 + 1];
            part[((long long)bz * 2048 + m0 + tid) * 32 + bx] =
                make_float2(M, S);
        }
    } else {
#pragma unroll
        for (int mi = 0; mi < MI; ++mi)
#pragma unroll
            for (int ni = 0; ni < NI; ++ni) {
                int colg = n0 + wn + ni * 16 + l15;
                float bv = bias ? bias[colg] : 0.f;
#pragma unroll
                for (int r = 0; r < 4; ++r) {
                    int rowg = m0 + wm + mi * 16 + quad * 4 + r;
                    float v = acc[mi][ni][r] + bv;
                    int seg = colg >> 10;   // mode 2: segmented fp16
                    Ch[(long long)seg * sC + (long long)rowg * 1024 +
                       (colg & 1023)] = f2h(v);
                }
            }
    }
}

// plain GEMM kernel (proj): m157 XCD remap + body, MODE 2
template <int TM, int TN, int MODE>
__global__ __launch_bounds__(256, 2)
void gemm_nt(const unsigned short* __restrict__ A,
             const unsigned short* __restrict__ B,
             const float* __restrict__ bias,
             unsigned short* __restrict__ Ch,
             int N, int K, long long sA, long long sB, long long sC) {
    __shared__ unsigned short smem[(TM + TN) * BK];
    int bx, by, bz;
    xcd_remap(bx, by, bz);
    gemm_body<TM, TN, MODE>(smem, bx, by, bz, A, B, bias, Ch, nullptr, N, K,
                            sA, sB, sC);
}

// ---------------------------------------------------------------------------
// scores + vT dispatch: 4096 blocks, 24KB LDS, pinned 6 blocks/CU.
// Physical block f -> XCD c = f&7, rank = f>>3.
// rank<256: scores GEMM block 128x64 (XCD-chunked, w = c*256+rank over the
// (32,16,4) grid), MODE 1 -> P~ fp16 + partials.
// rank>=256: one 64x64 v16->vT transpose tile (2048 tiles) backfilling.
// ---------------------------------------------------------------------------
__global__ __launch_bounds__(256, 6)
void scores_vT(const unsigned short* __restrict__ k16,
               const unsigned short* __restrict__ q16,
               unsigned short* __restrict__ P16,
               float2* __restrict__ part,
               const unsigned short* __restrict__ v,
               unsigned short* __restrict__ vT) {
    __shared__ unsigned short smem[(128 + 64) * BK];   // 24KB
    const int f = blockIdx.x;
    const int c = f & 7;
    const int rank = f >> 3;
    if (rank < 256) {
        const int w = c * 256 + rank;          // scores work id, XCD-chunked
        const int bx = w & 31;
        const int by = (w >> 5) & 15;
        const int bz = w >> 9;
        gemm_body<128, 64, 1>(smem, bx, by, bz, k16, q16, nullptr, P16, part,
                              2048, 1024,
                              (long long)2048 * 1024, (long long)2048 * 1024,
                              (long long)2048 * 2048);
    } else {
        // 64x64 transpose tile: t in [0,2048); 512 tiles per batch
        const int t = c * 256 + (rank - 256);
        auto tile = (unsigned short(*)[76])smem;   // 64x76 ushort = 9728B
        const int tid = threadIdx.x;
        int z = t >> 9;                  // batch
        int rest = t & 511;              // 16 a-tiles x 32 n-tiles
        int c0 = (rest & 15) * 64;       // a base
        int r0 = (rest >> 4) * 64;       // n base
        long long zs = (long long)z * 2048 * 1024;
        int tx = tid & 15, ty = tid >> 4;
#pragma unroll
        for (int j = 0; j < 4; ++j) {
            int r = ty + j * 16;
            ushort4 u = *(const ushort4*)(v + zs +
                                          (long long)(r0 + r) * 1024 + c0 + tx * 4);
            *(ushort4*)&tile[r][tx * 4] = u;
        }
        __syncthreads();
#pragma unroll
        for (int j = 0; j < 4; ++j) {
            int a = ty + j * 16;
            ushort4 u = make_ushort4(tile[tx * 4 + 0][a], tile[tx * 4 + 1][a],
                                     tile[tx * 4 + 2][a], tile[tx * 4 + 3][a]);
            *(ushort4*)(vT + zs + (long long)(c0 + a) * 2048 + r0 + tx * 4) = u;
        }
    }
}

// ---------------------------------------------------------------------------
// pv_fused (R16, unchanged): out = inv[n] * sum_t c[n,t] * (P~_t @ vT_t).
// Block 128x64 (grid 16x16x4), 256 thr.  Both operands via gll16; per
// K-tile MFMA into zeroed tmp, then acc += c_f32(row, tile) * tmp.
// ---------------------------------------------------------------------------
__global__ __launch_bounds__(256, 2)
void pv_fused(const unsigned short* __restrict__ P16,  // [4][2048][2048]
              const float2* __restrict__ part,          // [4][2048][32]
              const unsigned short* __restrict__ vT,    // [4][1024][2048]
              float* __restrict__ out) {                 // [4][2048][1024]
    constexpr int TM = 128, TN = 64, MI = 4, NI = 2, K = 2048;
    __shared__ unsigned short As[TM * BK];      // 16 KB
    __shared__ unsigned short Bs[TN * BK];      // 8 KB
    __shared__ unsigned short c16[TM][32];      // 8 KB
    __shared__ float invrow[TM];

    const int tid = threadIdx.x;
    const int lane = tid & 63;
    const int wave = tid >> 6;
    const int quad = lane >> 4;
    const int l15 = lane & 15;
    const int wm = (wave & 1) * 64;
    const int wn = (wave >> 1) * 32;

    int bx, by, bz;
    xcd_remap(bx, by, bz);                      // grid (16,16,4)
    const int m0 = by * TM;                     // n-row base
    const int n0 = bx * TN;                     // a-col base

    // ---- combine partials: thread pair (2 per row) over 16 slices each ----
    {
        const int row = tid >> 1;
        const int h = tid & 1;
        const float2* pp =
            part + ((long long)bz * 2048 + m0 + row) * 32 + h * 16;
        float pm[16], ps[16];
#pragma unroll
        for (int i = 0; i < 4; ++i) {
            float4 a = *(const float4*)(pp + i * 4);
            float4 b = *(const float4*)(pp + i * 4 + 2);
            pm[i * 4 + 0] = a.x; ps[i * 4 + 0] = a.y;
            pm[i * 4 + 1] = a.z; ps[i * 4 + 1] = a.w;
            pm[i * 4 + 2] = b.x; ps[i * 4 + 2] = b.y;
            pm[i * 4 + 3] = b.z; ps[i * 4 + 3] = b.w;
        }
        float m = pm[0];
#pragma unroll
        for (int i = 1; i < 16; ++i) m = fmaxf(m, pm[i]);
        float M = fmaxf(m, __shfl_xor(m, 1));   // pair = same row
        float s = 0.f;
#pragma unroll
        for (int i = 0; i < 16; ++i) s += ps[i] * __expf(pm[i] - M);
        s += __shfl_xor(s, 1);
        if (h == 0) invrow[row] = 1.0f / s;
#pragma unroll
        for (int i = 0; i < 16; ++i)
            c16[row][h * 16 + i] = f2h(__expf(pm[i] - M));
    }

    // staging geometry — identical to gemm_body (A=P~, B=vT, both K=2048)
    const int arow = wave * 32 + (lane >> 3);            // TM/4 = 32
    const int brow = wave * 16 + (lane >> 3);            // TN/4 = 16
    const int schunk8 = (((lane & 7) ^ ((lane >> 3) & 7)) << 3);
    const long long aoff =
        ((long long)bz * 2048 + m0 + arow) * 2048 + schunk8;
    const long long boff =
        ((long long)bz * 1024 + n0 + brow) * 2048 + schunk8;
    unsigned short* lA = As + (wave * 32) * BK;
    unsigned short* lB = Bs + (wave * 16) * BK;

    floatx4 zero = {0.f, 0.f, 0.f, 0.f};
    floatx4 acc[MI][NI];
#pragma unroll
    for (int i = 0; i < MI; ++i)
#pragma unroll
        for (int j = 0; j < NI; ++j) acc[i][j] = zero;

    __syncthreads();   // c16/invrow visible (distinct LDS from As/Bs)

    for (int k0 = 0; k0 < K; k0 += BK) {
#pragma unroll
        for (int j = 0; j < 4; ++j)
            gll16(P16 + aoff + k0 + (long long)j * 8 * 2048, lA + j * 8 * BK);
#pragma unroll
        for (int j = 0; j < 2; ++j)
            gll16(vT + boff + k0 + (long long)j * 8 * 2048, lB + j * 8 * BK);
        __syncthreads();

        floatx4 tmp[MI][NI];
#pragma unroll
        for (int i = 0; i < MI; ++i)
#pragma unroll
            for (int j = 0; j < NI; ++j) tmp[i][j] = zero;

#pragma unroll
        for (int t = 0; t < 2; ++t) {
            half8 a[MI], b[NI];
#pragma unroll
            for (int mi = 0; mi < MI; ++mi) {
                int r = wm + mi * 16 + l15;
                int p = (t * 4 + quad) ^ (r & 7);
                a[mi] = *(const half8*)&As[r * BK + p * 8];
            }
#pragma unroll
            for (int ni = 0; ni < NI; ++ni) {
                int r = wn + ni * 16 + l15;
                int p = (t * 4 + quad) ^ (r & 7);
                b[ni] = *(const half8*)&Bs[r * BK + p * 8];
            }
#pragma unroll
            for (int mi = 0; mi < MI; ++mi)
#pragma unroll
                for (int ni = 0; ni < NI; ++ni)
                    tmp[mi][ni] = MFMA16(a[mi], b[ni], tmp[mi][ni], 0, 0, 0);
        }

        // fold slice scale in fp32: acc += c(row, slice) * tmp
        const int jt = k0 >> 6;
#pragma unroll
        for (int mi = 0; mi < MI; ++mi)
#pragma unroll
            for (int r = 0; r < 4; ++r) {
                float cf = h2f(c16[wm + mi * 16 + quad * 4 + r][jt]);
#pragma unroll
                for (int ni = 0; ni < NI; ++ni)
                    acc[mi][ni][r] += cf * tmp[mi][ni][r];
            }
        __syncthreads();
    }

    // epilogue: out = acc * invrow
#pragma unroll
    for (int mi = 0; mi < MI; ++mi)
#pragma unroll
        for (int ni = 0; ni < NI; ++ni) {
            int colg = n0 + wn + ni * 16 + l15;
#pragma unroll
            for (int r = 0; r < 4; ++r) {
                int rowl = wm + mi * 16 + quad * 4 + r;
                out[((long long)bz * 2048 + m0 + rowl) * 1024 + colg] =
                    acc[mi][ni][r] * invrow[rowl];
            }
        }
}

// ---------------------------------------------------------------------------
extern "C" void kernel_launch(void* const* d_in, const int* in_sizes, int n_in,
                              void* d_out, int out_size, void* d_ws,
                              size_t ws_size, hipStream_t stream) {
    const float* x  = (const float*)d_in[0];
    const float* Wk = (const float*)d_in[1];
    const float* bk = (const float*)d_in[2];
    const float* Wq = (const float*)d_in[3];
    const float* bq = (const float*)d_in[4];
    const float* Wv = (const float*)d_in[5];
    const float* bv = (const float*)d_in[6];
    float* out = (float*)d_out;

    const int Bb = 4, Ns = 2048, E = 1024, Aa = 1024;
    const int M = Bb * Ns;  // 8192

    char* p = (char*)d_ws;
    auto alloc = [&](size_t bytes) {
        char* r = p;
        p += (bytes + 255) & ~(size_t)255;
        return r;
    };
    const size_t MA = (size_t)M * Aa;          // 8.39M elems
    unsigned short* x16 = (unsigned short*)alloc(MA * 2);
    unsigned short* WT  = (unsigned short*)alloc((size_t)3 * E * Aa * 2);
    // k16,q16,v16 MUST be contiguous (segmented epilogue): MA*2 is a
    // multiple of 256, so alloc() inserts no padding.
    unsigned short* k16 = (unsigned short*)alloc(MA * 2);
    unsigned short* q16 = (unsigned short*)alloc(MA * 2);
    unsigned short* v16 = (unsigned short*)alloc(MA * 2);
    unsigned short* vT  = (unsigned short*)alloc(MA * 2);
    unsigned short* p16 = (unsigned short*)alloc((size_t)M * Ns * 2);
    float2* part = (float2*)alloc((size_t)M * 32 * 8);
    float* bias3 = (float*)alloc(3072 * 4);

    // 1. prep: x->fp16, W^T x3 (64x64 tiles), bias concat
    prep<<<8972, 256, 0, stream>>>(x, Wk, Wq, Wv, bk, bq, bv, x16, WT, bias3);

    // 2. fused projections: [k|q|v] = x16 @ [Wk|Wq|Wv]^T + bias3  (1536 blk)
    gemm_nt<128, 128, 2><<<dim3(3 * Aa / 128, M / 128, 1), 256, 0, stream>>>(
        x16, WT, bias3, k16, 3 * Aa, E, 0, 0, (long long)MA);

    // 3. scores (2048 XCD-chunked 128x64 blocks, MODE 1 -> P~ + partials)
    //    + v->vT (2048 64x64 backfill tiles); 6 blocks/CU
    scores_vT<<<4096, 256, 0, stream>>>(k16, q16, p16, part, v16, vT);

    // 4. pv_fused: combine partials + per-tile accumulator rescale (1024 blk)
    pv_fused<<<dim3(16, 16, 4), 256, 0, stream>>>(p16, part, vT, out);
}

// Round 10
// 259.943 us; speedup vs baseline: 1.0104x; 1.0104x over previous
//
#include <hip/hip_runtime.h>

// ---------------------------------------------------------------------------
// SelfAttention: out = softmax((x@Wk+bk) @ (x@Wq+bq)^T) @ (x@Wv+bv)
// B=4, N=2048, E=A=1024, fp32 in/out.
// R18 = R17 minus self-inflicted damage (R17: lb(256,6) pinned VGPR=40 ->
// scratch spills, MfmaUtil 21.6%; epilogue [TM][2] combine = 786K bank
// conflicts):
//  - scores_vT back to __launch_bounds__(256,2): VGPR free (~64); residency
//    still 6 blocks/CU (LDS-limited: 24KB -> floor(160/24) = 6).
//  - MODE-1 combine buffers re-laid out [2][TM] (stride-1 writes, broadcast
//    reads) -> conflict-free.
//  - prep / proj / pv_fused unchanged; numerics unchanged (absmax 0.08081).
// ---------------------------------------------------------------------------

typedef __attribute__((ext_vector_type(8))) _Float16 half8;   // 4 VGPRs
typedef __attribute__((ext_vector_type(4))) float floatx4;

#define BK 64
#define MFMA16 __builtin_amdgcn_mfma_f32_16x16x32_f16

static __device__ __forceinline__ unsigned short f2h(float f) {
    _Float16 h = (_Float16)f;          // RNE
    return *(unsigned short*)&h;
}
static __device__ __forceinline__ float h2f(unsigned short u) {
    _Float16 h = *(_Float16*)&u;
    return (float)h;
}

// async global->LDS, 16B per lane; LDS dst = wave-uniform base + lane*16
static __device__ __forceinline__ void gll16(const unsigned short* g,
                                             unsigned short* l) {
    __builtin_amdgcn_global_load_lds(
        (__attribute__((address_space(1))) void*)(g),
        (__attribute__((address_space(3))) void*)(l), 16, 0, 0);
}

// XCD-chunked bijective remap (m157; requires nwg % 8 == 0).
static __device__ __forceinline__ void xcd_remap(int& bx, int& by, int& bz) {
    const int gx = gridDim.x, gy = gridDim.y, gz = gridDim.z;
    const int flat = blockIdx.x + gx * (blockIdx.y + gy * blockIdx.z);
    const int w = (flat & 7) * ((gx * gy * gz) >> 3) + (flat >> 3);
    bx = w % gx;
    const int r = w / gx;
    by = r % gy;
    bz = r / gy;
}

// ---------------------------------------------------------------------------
// prep: blocks 0..8191 cast x -> fp16;
//       8192..8959: 64x64 W-transpose tiles (256 per W, 3 Ws) -> WT fp16;
//       8960..8971: bias concat (12 blocks x 256 = 3072).
// ---------------------------------------------------------------------------
__global__ __launch_bounds__(256)
void prep(const float* __restrict__ x,
          const float* __restrict__ W0, const float* __restrict__ W1,
          const float* __restrict__ W2,
          const float* __restrict__ b0, const float* __restrict__ b1,
          const float* __restrict__ b2,
          unsigned short* __restrict__ x16, unsigned short* __restrict__ WT,
          float* __restrict__ bias3) {
    __shared__ unsigned short wtile[64][76];   // pad 76: 152B row, 8B-aligned
    const int bid = blockIdx.x;
    const int tid = threadIdx.x;
    if (bid < 8192) {
        int i = bid * 1024 + tid * 4;
        float4 f = *(const float4*)(x + i);
        *(ushort4*)(x16 + i) =
            make_ushort4(f2h(f.x), f2h(f.y), f2h(f.z), f2h(f.w));
    } else if (bid < 8960) {
        int wz = bid - 8192;
        int z = wz >> 8;                     // which W (256 tiles each)
        int t = wz & 255;
        const float* W = z == 0 ? W0 : (z == 1 ? W1 : W2);
        unsigned short* Tz = WT + (size_t)z * 1024 * 1024;
        int c0 = (t & 15) * 64, r0 = (t >> 4) * 64;
        int tx = tid & 15, ty = tid >> 4;
#pragma unroll
        for (int j = 0; j < 4; ++j) {
            int r = ty + j * 16;
            float4 f = *(const float4*)(W + (r0 + r) * 1024 + c0 + tx * 4);
            *(ushort4*)&wtile[r][tx * 4] =
                make_ushort4(f2h(f.x), f2h(f.y), f2h(f.z), f2h(f.w));
        }
        __syncthreads();
#pragma unroll
        for (int j = 0; j < 4; ++j) {
            int a = ty + j * 16;
            ushort4 u = make_ushort4(wtile[tx * 4 + 0][a], wtile[tx * 4 + 1][a],
                                     wtile[tx * 4 + 2][a], wtile[tx * 4 + 3][a]);
            *(ushort4*)(Tz + (size_t)(c0 + a) * 1024 + r0 + tx * 4) = u;
        }
    } else {
        int i = (bid - 8960) * 256 + tid;    // 12*256 = 3072
        int s = i >> 10;
        const float* b = s == 0 ? b0 : (s == 1 ? b1 : b2);
        bias3[i] = b[i & 1023];
    }
}

// ---------------------------------------------------------------------------
// NT GEMM body (R11 structure, 2-barrier single-buffer):
// C[M,N] = A[M,K]*B[N,K]^T; fp16 in, fp32 acc.  Block TM x TN, 256 thr
// (4 waves 2x2; wave tile TM/2 x TN/2), BK=64.  LDS: unpadded [row][64],
// XOR chunk swizzle (pos p of row r holds chunk p ^ (r&7)) — conflict-free.
// MODE 1 (requires TN==64): softmax-prep epilogue, block == one 64-col
//   slice: two-phase LDS combine ([2][TM] buffers, conflict-free) ->
//   P~ = fp16(exp(s - sliceM)) -> Ch, part[row][slice] = (sliceM, sumexp).
// MODE 2: fp16 segmented (+bias) -> Ch (k|q|v contiguous).
// ---------------------------------------------------------------------------
template <int TM, int TN, int MODE>
static __device__ __forceinline__ void gemm_body(
    unsigned short* smem, int bx, int by, int bz,
    const unsigned short* __restrict__ A,
    const unsigned short* __restrict__ B,
    const float* __restrict__ bias,
    unsigned short* __restrict__ Ch, float2* __restrict__ part,
    int N, int K, long long sA, long long sB, long long sC) {
    constexpr int WM = TM / 2;       // wave tile rows
    constexpr int MI = WM / 16;      // acc row-tiles per wave
    constexpr int WN = TN / 2;
    constexpr int NI = WN / 16;      // acc col-tiles per wave
    unsigned short* As = smem;                  // TM x BK
    unsigned short* Bs = smem + TM * BK;        // TN x BK

    const int tid = threadIdx.x;
    const int lane = tid & 63;
    const int wave = tid >> 6;          // 0..3
    const int quad = lane >> 4;
    const int l15 = lane & 15;
    const int wm = (wave & 1) * WM;
    const int wn = (wave >> 1) * WN;

    const long long zA = (long long)bz * sA;
    const long long zB = (long long)bz * sB;
    const long long zC = (long long)bz * sC;
    const int m0 = by * TM;
    const int n0 = bx * TN;

    // staging: lane i covers row i>>3; position p=i&7 gets chunk p ^ (row&7)
    const int arow = wave * (TM / 4) + (lane >> 3);
    const int brow = wave * (TN / 4) + (lane >> 3);
    const int schunk8 = (((lane & 7) ^ ((lane >> 3) & 7)) << 3);
    const long long aoff = zA + (long long)(m0 + arow) * K + schunk8;
    const long long boff = zB + (long long)(n0 + brow) * K + schunk8;
    unsigned short* lA = As + (wave * (TM / 4)) * BK;
    unsigned short* lB = Bs + (wave * (TN / 4)) * BK;

    floatx4 zero = {0.f, 0.f, 0.f, 0.f};
    floatx4 acc[MI][NI];
#pragma unroll
    for (int i = 0; i < MI; ++i)
#pragma unroll
        for (int j = 0; j < NI; ++j) acc[i][j] = zero;

    for (int k0 = 0; k0 < K; k0 += BK) {
        __syncthreads();
#pragma unroll
        for (int j = 0; j < TM / 32; ++j)
            gll16(A + aoff + k0 + (long long)j * 8 * K, lA + j * 8 * BK);
#pragma unroll
        for (int j = 0; j < TN / 32; ++j)
            gll16(B + boff + k0 + (long long)j * 8 * K, lB + j * 8 * BK);
        __syncthreads();

#pragma unroll
        for (int t = 0; t < 2; ++t) {      // two K=32 MFMA steps per BK=64
            half8 a[MI], b[NI];
#pragma unroll
            for (int mi = 0; mi < MI; ++mi) {
                int r = wm + mi * 16 + l15;
                int p = (t * 4 + quad) ^ (r & 7);
                a[mi] = *(const half8*)&As[r * BK + p * 8];
            }
#pragma unroll
            for (int ni = 0; ni < NI; ++ni) {
                int r = wn + ni * 16 + l15;
                int p = (t * 4 + quad) ^ (r & 7);
                b[ni] = *(const half8*)&Bs[r * BK + p * 8];
            }
#pragma unroll
            for (int mi = 0; mi < MI; ++mi)
#pragma unroll
                for (int ni = 0; ni < NI; ++ni)
                    acc[mi][ni] = MFMA16(a[mi], b[ni], acc[mi][ni], 0, 0, 0);
        }
    }

    // epilogue: C/D layout col=lane&15, row=quad*4+reg  [verified m89/m91]
    if constexpr (MODE == 1) {
        // TN==64: block spans exactly slice bx.  Cross-wave combine via LDS.
        // Buffers [2][TM]: writes stride-1 across rows (conflict-free);
        // phase-2 reads are 16-lane same-address broadcasts (free).
        __syncthreads();
        float* bufm = (float*)smem;            // [2][TM]
        float* bufs = bufm + 2 * TM;           // [2][TM]
        const int half = wn >> 5;              // 0|1
        // phase 1: 32-col max per row-half
#pragma unroll
        for (int mi = 0; mi < MI; ++mi)
#pragma unroll
            for (int r = 0; r < 4; ++r) {
                float mx = acc[mi][0][r];
#pragma unroll
                for (int ni = 1; ni < NI; ++ni)
                    mx = fmaxf(mx, acc[mi][ni][r]);
#pragma unroll
                for (int off = 1; off <= 8; off <<= 1)
                    mx = fmaxf(mx, __shfl_xor(mx, off));
                if (l15 == 0)
                    bufm[half * TM + wm + mi * 16 + quad * 4 + r] = mx;
            }
        __syncthreads();
        // phase 2: slice max -> write P~, accumulate 32-col sums
#pragma unroll
        for (int mi = 0; mi < MI; ++mi)
#pragma unroll
            for (int r = 0; r < 4; ++r) {
                const int rowl = wm + mi * 16 + quad * 4 + r;
                const float M = fmaxf(bufm[rowl], bufm[TM + rowl]);
                float sm = 0.f;
#pragma unroll
                for (int ni = 0; ni < NI; ++ni) {
                    float e = __expf(acc[mi][ni][r] - M);
                    sm += e;
                    Ch[zC + (long long)(m0 + rowl) * N + n0 + wn + ni * 16 +
                       l15] = f2h(e);
                }
#pragma unroll
                for (int off = 1; off <= 8; off <<= 1)
                    sm += __shfl_xor(sm, off);
                if (l15 == 0) bufs[half * TM + rowl] = sm;
            }
        __syncthreads();
        // phase 3: one thread per row writes (M, S)
        if (tid < TM) {
            const float M = fmaxf(bufm[tid], bufm[TM + tid]);
            const float S = bufs[tid] + bufs[TM + tid];
            part[((long long)bz * 2048 + m0 + tid) * 32 + bx] =
                make_float2(M, S);
        }
    } else {
#pragma unroll
        for (int mi = 0; mi < MI; ++mi)
#pragma unroll
            for (int ni = 0; ni < NI; ++ni) {
                int colg = n0 + wn + ni * 16 + l15;
                float bv = bias ? bias[colg] : 0.f;
#pragma unroll
                for (int r = 0; r < 4; ++r) {
                    int rowg = m0 + wm + mi * 16 + quad * 4 + r;
                    float v = acc[mi][ni][r] + bv;
                    int seg = colg >> 10;   // mode 2: segmented fp16
                    Ch[(long long)seg * sC + (long long)rowg * 1024 +
                       (colg & 1023)] = f2h(v);
                }
            }
    }
}

// plain GEMM kernel (proj): m157 XCD remap + body, MODE 2
template <int TM, int TN, int MODE>
__global__ __launch_bounds__(256, 2)
void gemm_nt(const unsigned short* __restrict__ A,
             const unsigned short* __restrict__ B,
             const float* __restrict__ bias,
             unsigned short* __restrict__ Ch,
             int N, int K, long long sA, long long sB, long long sC) {
    __shared__ unsigned short smem[(TM + TN) * BK];
    int bx, by, bz;
    xcd_remap(bx, by, bz);
    gemm_body<TM, TN, MODE>(smem, bx, by, bz, A, B, bias, Ch, nullptr, N, K,
                            sA, sB, sC);
}

// ---------------------------------------------------------------------------
// scores + vT dispatch: 4096 blocks, 24KB LDS (-> 6 blocks/CU, LDS-limited).
// Physical block f -> XCD c = f&7, rank = f>>3.
// rank<256: scores GEMM block 128x64 (XCD-chunked, w = c*256+rank over the
// (32,16,4) grid), MODE 1 -> P~ fp16 + partials.
// rank>=256: one 64x64 v16->vT transpose tile (2048 tiles) backfilling.
// ---------------------------------------------------------------------------
__global__ __launch_bounds__(256, 2)
void scores_vT(const unsigned short* __restrict__ k16,
               const unsigned short* __restrict__ q16,
               unsigned short* __restrict__ P16,
               float2* __restrict__ part,
               const unsigned short* __restrict__ v,
               unsigned short* __restrict__ vT) {
    __shared__ unsigned short smem[(128 + 64) * BK];   // 24KB
    const int f = blockIdx.x;
    const int c = f & 7;
    const int rank = f >> 3;
    if (rank < 256) {
        const int w = c * 256 + rank;          // scores work id, XCD-chunked
        const int bx = w & 31;
        const int by = (w >> 5) & 15;
        const int bz = w >> 9;
        gemm_body<128, 64, 1>(smem, bx, by, bz, k16, q16, nullptr, P16, part,
                              2048, 1024,
                              (long long)2048 * 1024, (long long)2048 * 1024,
                              (long long)2048 * 2048);
    } else {
        // 64x64 transpose tile: t in [0,2048); 512 tiles per batch
        const int t = c * 256 + (rank - 256);
        auto tile = (unsigned short(*)[76])smem;   // 64x76 ushort = 9728B
        const int tid = threadIdx.x;
        int z = t >> 9;                  // batch
        int rest = t & 511;              // 16 a-tiles x 32 n-tiles
        int c0 = (rest & 15) * 64;       // a base
        int r0 = (rest >> 4) * 64;       // n base
        long long zs = (long long)z * 2048 * 1024;
        int tx = tid & 15, ty = tid >> 4;
#pragma unroll
        for (int j = 0; j < 4; ++j) {
            int r = ty + j * 16;
            ushort4 u = *(const ushort4*)(v + zs +
                                          (long long)(r0 + r) * 1024 + c0 + tx * 4);
            *(ushort4*)&tile[r][tx * 4] = u;
        }
        __syncthreads();
#pragma unroll
        for (int j = 0; j < 4; ++j) {
            int a = ty + j * 16;
            ushort4 u = make_ushort4(tile[tx * 4 + 0][a], tile[tx * 4 + 1][a],
                                     tile[tx * 4 + 2][a], tile[tx * 4 + 3][a]);
            *(ushort4*)(vT + zs + (long long)(c0 + a) * 2048 + r0 + tx * 4) = u;
        }
    }
}

// ---------------------------------------------------------------------------
// pv_fused (R16, unchanged): out = inv[n] * sum_t c[n,t] * (P~_t @ vT_t).
// Block 128x64 (grid 16x16x4), 256 thr.  Both operands via gll16; per
// K-tile MFMA into zeroed tmp, then acc += c_f32(row, tile) * tmp.
// ---------------------------------------------------------------------------
__global__ __launch_bounds__(256, 2)
void pv_fused(const unsigned short* __restrict__ P16,  // [4][2048][2048]
              const float2* __restrict__ part,          // [4][2048][32]
              const unsigned short* __restrict__ vT,    // [4][1024][2048]
              float* __restrict__ out) {                 // [4][2048][1024]
    constexpr int TM = 128, TN = 64, MI = 4, NI = 2, K = 2048;
    __shared__ unsigned short As[TM * BK];      // 16 KB
    __shared__ unsigned short Bs[TN * BK];      // 8 KB
    __shared__ unsigned short c16[TM][32];      // 8 KB
    __shared__ float invrow[TM];

    const int tid = threadIdx.x;
    const int lane = tid & 63;
    const int wave = tid >> 6;
    const int quad = lane >> 4;
    const int l15 = lane & 15;
    const int wm = (wave & 1) * 64;
    const int wn = (wave >> 1) * 32;

    int bx, by, bz;
    xcd_remap(bx, by, bz);                      // grid (16,16,4)
    const int m0 = by * TM;                     // n-row base
    const int n0 = bx * TN;                     // a-col base

    // ---- combine partials: thread pair (2 per row) over 16 slices each ----
    {
        const int row = tid >> 1;
        const int h = tid & 1;
        const float2* pp =
            part + ((long long)bz * 2048 + m0 + row) * 32 + h * 16;
        float pm[16], ps[16];
#pragma unroll
        for (int i = 0; i < 4; ++i) {
            float4 a = *(const float4*)(pp + i * 4);
            float4 b = *(const float4*)(pp + i * 4 + 2);
            pm[i * 4 + 0] = a.x; ps[i * 4 + 0] = a.y;
            pm[i * 4 + 1] = a.z; ps[i * 4 + 1] = a.w;
            pm[i * 4 + 2] = b.x; ps[i * 4 + 2] = b.y;
            pm[i * 4 + 3] = b.z; ps[i * 4 + 3] = b.w;
        }
        float m = pm[0];
#pragma unroll
        for (int i = 1; i < 16; ++i) m = fmaxf(m, pm[i]);
        float M = fmaxf(m, __shfl_xor(m, 1));   // pair = same row
        float s = 0.f;
#pragma unroll
        for (int i = 0; i < 16; ++i) s += ps[i] * __expf(pm[i] - M);
        s += __shfl_xor(s, 1);
        if (h == 0) invrow[row] = 1.0f / s;
#pragma unroll
        for (int i = 0; i < 16; ++i)
            c16[row][h * 16 + i] = f2h(__expf(pm[i] - M));
    }

    // staging geometry — identical to gemm_body (A=P~, B=vT, both K=2048)
    const int arow = wave * 32 + (lane >> 3);            // TM/4 = 32
    const int brow = wave * 16 + (lane >> 3);            // TN/4 = 16
    const int schunk8 = (((lane & 7) ^ ((lane >> 3) & 7)) << 3);
    const long long aoff =
        ((long long)bz * 2048 + m0 + arow) * 2048 + schunk8;
    const long long boff =
        ((long long)bz * 1024 + n0 + brow) * 2048 + schunk8;
    unsigned short* lA = As + (wave * 32) * BK;
    unsigned short* lB = Bs + (wave * 16) * BK;

    floatx4 zero = {0.f, 0.f, 0.f, 0.f};
    floatx4 acc[MI][NI];
#pragma unroll
    for (int i = 0; i < MI; ++i)
#pragma unroll
        for (int j = 0; j < NI; ++j) acc[i][j] = zero;

    __syncthreads();   // c16/invrow visible (distinct LDS from As/Bs)

    for (int k0 = 0; k0 < K; k0 += BK) {
#pragma unroll
        for (int j = 0; j < 4; ++j)
            gll16(P16 + aoff + k0 + (long long)j * 8 * 2048, lA + j * 8 * BK);
#pragma unroll
        for (int j = 0; j < 2; ++j)
            gll16(vT + boff + k0 + (long long)j * 8 * 2048, lB + j * 8 * BK);
        __syncthreads();

        floatx4 tmp[MI][NI];
#pragma unroll
        for (int i = 0; i < MI; ++i)
#pragma unroll
            for (int j = 0; j < NI; ++j) tmp[i][j] = zero;

#pragma unroll
        for (int t = 0; t < 2; ++t) {
            half8 a[MI], b[NI];
#pragma unroll
            for (int mi = 0; mi < MI; ++mi) {
                int r = wm + mi * 16 + l15;
                int p = (t * 4 + quad) ^ (r & 7);
                a[mi] = *(const half8*)&As[r * BK + p * 8];
            }
#pragma unroll
            for (int ni = 0; ni < NI; ++ni) {
                int r = wn + ni * 16 + l15;
                int p = (t * 4 + quad) ^ (r & 7);
                b[ni] = *(const half8*)&Bs[r * BK + p * 8];
            }
#pragma unroll
            for (int mi = 0; mi < MI; ++mi)
#pragma unroll
                for (int ni = 0; ni < NI; ++ni)
                    tmp[mi][ni] = MFMA16(a[mi], b[ni], tmp[mi][ni], 0, 0, 0);
        }

        // fold slice scale in fp32: acc += c(row, slice) * tmp
        const int jt = k0 >> 6;
#pragma unroll
        for (int mi = 0; mi < MI; ++mi)
#pragma unroll
            for (int r = 0; r < 4; ++r) {
                float cf = h2f(c16[wm + mi * 16 + quad * 4 + r][jt]);
#pragma unroll
                for (int ni = 0; ni < NI; ++ni)
                    acc[mi][ni][r] += cf * tmp[mi][ni][r];
            }
        __syncthreads();
    }

    // epilogue: out = acc * invrow
#pragma unroll
    for (int mi = 0; mi < MI; ++mi)
#pragma unroll
        for (int ni = 0; ni < NI; ++ni) {
            int colg = n0 + wn + ni * 16 + l15;
#pragma unroll
            for (int r = 0; r < 4; ++r) {
                int rowl = wm + mi * 16 + quad * 4 + r;
                out[((long long)bz * 2048 + m0 + rowl) * 1024 + colg] =
                    acc[mi][ni][r] * invrow[rowl];
            }
        }
}

// ---------------------------------------------------------------------------
extern "C" void kernel_launch(void* const* d_in, const int* in_sizes, int n_in,
                              void* d_out, int out_size, void* d_ws,
                              size_t ws_size, hipStream_t stream) {
    const float* x  = (const float*)d_in[0];
    const float* Wk = (const float*)d_in[1];
    const float* bk = (const float*)d_in[2];
    const float* Wq = (const float*)d_in[3];
    const float* bq = (const float*)d_in[4];
    const float* Wv = (const float*)d_in[5];
    const float* bv = (const float*)d_in[6];
    float* out = (float*)d_out;

    const int Bb = 4, Ns = 2048, E = 1024, Aa = 1024;
    const int M = Bb * Ns;  // 8192

    char* p = (char*)d_ws;
    auto alloc = [&](size_t bytes) {
        char* r = p;
        p += (bytes + 255) & ~(size_t)255;
        return r;
    };
    const size_t MA = (size_t)M * Aa;          // 8.39M elems
    unsigned short* x16 = (unsigned short*)alloc(MA * 2);
    unsigned short* WT  = (unsigned short*)alloc((size_t)3 * E * Aa * 2);
    // k16,q16,v16 MUST be contiguous (segmented epilogue): MA*2 is a
    // multiple of 256, so alloc() inserts no padding.
    unsigned short* k16 = (unsigned short*)alloc(MA * 2);
    unsigned short* q16 = (unsigned short*)alloc(MA * 2);
    unsigned short* v16 = (unsigned short*)alloc(MA * 2);
    unsigned short* vT  = (unsigned short*)alloc(MA * 2);
    unsigned short* p16 = (unsigned short*)alloc((size_t)M * Ns * 2);
    float2* part = (float2*)alloc((size_t)M * 32 * 8);
    float* bias3 = (float*)alloc(3072 * 4);

    // 1. prep: x->fp16, W^T x3 (64x64 tiles), bias concat
    prep<<<8972, 256, 0, stream>>>(x, Wk, Wq, Wv, bk, bq, bv, x16, WT, bias3);

    // 2. fused projections: [k|q|v] = x16 @ [Wk|Wq|Wv]^T + bias3  (1536 blk)
    gemm_nt<128, 128, 2><<<dim3(3 * Aa / 128, M / 128, 1), 256, 0, stream>>>(
        x16, WT, bias3, k16, 3 * Aa, E, 0, 0, (long long)MA);

    // 3. scores (2048 XCD-chunked 128x64 blocks, MODE 1 -> P~ + partials)
    //    + v->vT (2048 64x64 backfill tiles); 6 blocks/CU (LDS-limited)
    scores_vT<<<4096, 256, 0, stream>>>(k16, q16, p16, part, v16, vT);

    // 4. pv_fused: combine partials + per-tile accumulator rescale (1024 blk)
    pv_fused<<<dim3(16, 16, 4), 256, 0, stream>>>(p16, part, vT, out);
}

// Round 11
// 244.959 us; speedup vs baseline: 1.0722x; 1.0612x over previous
//
#include <hip/hip_runtime.h>

// ---------------------------------------------------------------------------
// SelfAttention: out = softmax((x@Wk+bk) @ (x@Wq+bq)^T) @ (x@Wv+bv)
// B=4, N=2048, E=A=1024, fp32 in/out.
// R19 = R16 (session best, 255.5us) + counter-backed fixes:
//  - scores back to 128x128 (R17/R18's TN=64: per-FLOP efficiency loss
//    dominated the residency gain -- MfmaUtil 36->21.6%).
//  - transpose tiles (prep W, scores_vT v) pad 76->78: dword stride
//    156 % 32 = 28, gcd 4 -> 2 lanes/bank = free.  Kills the 786K
//    SQ_LDS_BANK_CONFLICT present since R14 (was misattributed in R18).
//  - pv_fused: fold 1/S into c' = fp16(exp(Mt-M)/S) at entry; invrow
//    deleted -> LDS exactly 32KB -> 5 blocks/CU (was 33.3KB = 4).
//    Epilogue writes acc directly.  Error magnitude unchanged (~5e-4 rel).
// 4 dispatches: prep, proj, scores_vT, pv_fused.
// ---------------------------------------------------------------------------

typedef __attribute__((ext_vector_type(8))) _Float16 half8;   // 4 VGPRs
typedef __attribute__((ext_vector_type(4))) float floatx4;

#define BK 64
#define MFMA16 __builtin_amdgcn_mfma_f32_16x16x32_f16

static __device__ __forceinline__ unsigned short f2h(float f) {
    _Float16 h = (_Float16)f;          // RNE
    return *(unsigned short*)&h;
}
static __device__ __forceinline__ float h2f(unsigned short u) {
    _Float16 h = *(_Float16*)&u;
    return (float)h;
}

// async global->LDS, 16B per lane; LDS dst = wave-uniform base + lane*16
static __device__ __forceinline__ void gll16(const unsigned short* g,
                                             unsigned short* l) {
    __builtin_amdgcn_global_load_lds(
        (__attribute__((address_space(1))) void*)(g),
        (__attribute__((address_space(3))) void*)(l), 16, 0, 0);
}

// XCD-chunked bijective remap (m157; requires nwg % 8 == 0).
static __device__ __forceinline__ void xcd_remap(int& bx, int& by, int& bz) {
    const int gx = gridDim.x, gy = gridDim.y, gz = gridDim.z;
    const int flat = blockIdx.x + gx * (blockIdx.y + gy * blockIdx.z);
    const int w = (flat & 7) * ((gx * gy * gz) >> 3) + (flat >> 3);
    bx = w % gx;
    const int r = w / gx;
    by = r % gy;
    bz = r / gy;
}

// ---------------------------------------------------------------------------
// prep: blocks 0..8191 cast x -> fp16;
//       8192..8959: 64x64 W-transpose tiles (256 per W, 3 Ws) -> WT fp16;
//       8960..8971: bias concat (12 blocks x 256 = 3072).
// ---------------------------------------------------------------------------
__global__ __launch_bounds__(256)
void prep(const float* __restrict__ x,
          const float* __restrict__ W0, const float* __restrict__ W1,
          const float* __restrict__ W2,
          const float* __restrict__ b0, const float* __restrict__ b1,
          const float* __restrict__ b2,
          unsigned short* __restrict__ x16, unsigned short* __restrict__ WT,
          float* __restrict__ bias3) {
    __shared__ unsigned short wtile[64][78];   // pad 78: 2-way (free) banks
    const int bid = blockIdx.x;
    const int tid = threadIdx.x;
    if (bid < 8192) {
        int i = bid * 1024 + tid * 4;
        float4 f = *(const float4*)(x + i);
        *(ushort4*)(x16 + i) =
            make_ushort4(f2h(f.x), f2h(f.y), f2h(f.z), f2h(f.w));
    } else if (bid < 8960) {
        int wz = bid - 8192;
        int z = wz >> 8;                     // which W (256 tiles each)
        int t = wz & 255;
        const float* W = z == 0 ? W0 : (z == 1 ? W1 : W2);
        unsigned short* Tz = WT + (size_t)z * 1024 * 1024;
        int c0 = (t & 15) * 64, r0 = (t >> 4) * 64;
        int tx = tid & 15, ty = tid >> 4;
#pragma unroll
        for (int j = 0; j < 4; ++j) {
            int r = ty + j * 16;
            float4 f = *(const float4*)(W + (r0 + r) * 1024 + c0 + tx * 4);
            *(ushort4*)&wtile[r][tx * 4] =
                make_ushort4(f2h(f.x), f2h(f.y), f2h(f.z), f2h(f.w));
        }
        __syncthreads();
#pragma unroll
        for (int j = 0; j < 4; ++j) {
            int a = ty + j * 16;
            ushort4 u = make_ushort4(wtile[tx * 4 + 0][a], wtile[tx * 4 + 1][a],
                                     wtile[tx * 4 + 2][a], wtile[tx * 4 + 3][a]);
            *(ushort4*)(Tz + (size_t)(c0 + a) * 1024 + r0 + tx * 4) = u;
        }
    } else {
        int i = (bid - 8960) * 256 + tid;    // 12*256 = 3072
        int s = i >> 10;
        const float* b = s == 0 ? b0 : (s == 1 ? b1 : b2);
        bias3[i] = b[i & 1023];
    }
}

// ---------------------------------------------------------------------------
// NT GEMM body (R11 structure, 2-barrier single-buffer, 36% MfmaUtil):
// C[M,N] = A[M,K]*B[N,K]^T; fp16 in, fp32 acc.  Block TM x TN, 256 thr
// (4 waves 2x2; wave tile TM/2 x TN/2), BK=64.  LDS: unpadded [row][64],
// XOR chunk swizzle (pos p of row r holds chunk p ^ (r&7)) — conflict-free.
// mode 1: softmax-prep epilogue (TN=128): in-wave 64-col slice reduce,
//   P~ = fp16(exp(s - slicemax)) -> Ch, part[row][slice]=(max,sumexp),
//   slice = bx*2 + (wave>>1).
// mode 2: fp16 segmented (+bias) -> Ch (k|q|v contiguous).
// ---------------------------------------------------------------------------
template <int TM, int TN>
static __device__ __forceinline__ void gemm_body(
    unsigned short* smem, int bx, int by, int bz,
    const unsigned short* __restrict__ A,
    const unsigned short* __restrict__ B,
    const float* __restrict__ bias,
    unsigned short* __restrict__ Ch, float2* __restrict__ part,
    int mode, int N, int K, long long sA, long long sB, long long sC) {
    constexpr int WM = TM / 2;       // wave tile rows
    constexpr int MI = WM / 16;      // acc row-tiles per wave
    constexpr int WN = TN / 2;
    constexpr int NI = WN / 16;      // acc col-tiles per wave
    unsigned short* As = smem;                  // TM x BK
    unsigned short* Bs = smem + TM * BK;        // TN x BK

    const int tid = threadIdx.x;
    const int lane = tid & 63;
    const int wave = tid >> 6;          // 0..3
    const int quad = lane >> 4;
    const int l15 = lane & 15;
    const int wm = (wave & 1) * WM;
    const int wn = (wave >> 1) * WN;

    const long long zA = (long long)bz * sA;
    const long long zB = (long long)bz * sB;
    const long long zC = (long long)bz * sC;
    const int m0 = by * TM;
    const int n0 = bx * TN;

    // staging: lane i covers row i>>3; position p=i&7 gets chunk p ^ (row&7)
    const int arow = wave * (TM / 4) + (lane >> 3);
    const int brow = wave * (TN / 4) + (lane >> 3);
    const int schunk8 = (((lane & 7) ^ ((lane >> 3) & 7)) << 3);
    const long long aoff = zA + (long long)(m0 + arow) * K + schunk8;
    const long long boff = zB + (long long)(n0 + brow) * K + schunk8;
    unsigned short* lA = As + (wave * (TM / 4)) * BK;
    unsigned short* lB = Bs + (wave * (TN / 4)) * BK;

    floatx4 zero = {0.f, 0.f, 0.f, 0.f};
    floatx4 acc[MI][NI];
#pragma unroll
    for (int i = 0; i < MI; ++i)
#pragma unroll
        for (int j = 0; j < NI; ++j) acc[i][j] = zero;

    for (int k0 = 0; k0 < K; k0 += BK) {
        __syncthreads();
#pragma unroll
        for (int j = 0; j < TM / 32; ++j)
            gll16(A + aoff + k0 + (long long)j * 8 * K, lA + j * 8 * BK);
#pragma unroll
        for (int j = 0; j < TN / 32; ++j)
            gll16(B + boff + k0 + (long long)j * 8 * K, lB + j * 8 * BK);
        __syncthreads();

#pragma unroll
        for (int t = 0; t < 2; ++t) {      // two K=32 MFMA steps per BK=64
            half8 a[MI], b[NI];
#pragma unroll
            for (int mi = 0; mi < MI; ++mi) {
                int r = wm + mi * 16 + l15;
                int p = (t * 4 + quad) ^ (r & 7);
                a[mi] = *(const half8*)&As[r * BK + p * 8];
            }
#pragma unroll
            for (int ni = 0; ni < NI; ++ni) {
                int r = wn + ni * 16 + l15;
                int p = (t * 4 + quad) ^ (r & 7);
                b[ni] = *(const half8*)&Bs[r * BK + p * 8];
            }
#pragma unroll
            for (int mi = 0; mi < MI; ++mi)
#pragma unroll
                for (int ni = 0; ni < NI; ++ni)
                    acc[mi][ni] = MFMA16(a[mi], b[ni], acc[mi][ni], 0, 0, 0);
        }
    }

    // epilogue: C/D layout col=lane&15, row=quad*4+reg  [verified m89/m91]
    if (mode == 1) {
        // per (mi,r): reduce over the wave's 64-col slice (ni in-reg, l15
        // via shfl_xor 1/2/4/8 — stays within quad). slice = bx*2+(wave>>1).
#pragma unroll
        for (int mi = 0; mi < MI; ++mi)
#pragma unroll
            for (int r = 0; r < 4; ++r) {
                float mx = acc[mi][0][r];
#pragma unroll
                for (int ni = 1; ni < NI; ++ni) mx = fmaxf(mx, acc[mi][ni][r]);
#pragma unroll
                for (int off = 1; off <= 8; off <<= 1)
                    mx = fmaxf(mx, __shfl_xor(mx, off));
                float sm = 0.f;
#pragma unroll
                for (int ni = 0; ni < NI; ++ni)
                    sm += __expf(acc[mi][ni][r] - mx);
#pragma unroll
                for (int off = 1; off <= 8; off <<= 1)
                    sm += __shfl_xor(sm, off);
                const int rowg = m0 + wm + mi * 16 + quad * 4 + r;
#pragma unroll
                for (int ni = 0; ni < NI; ++ni) {
                    int colg = n0 + wn + ni * 16 + l15;
                    Ch[zC + (long long)rowg * N + colg] =
                        f2h(__expf(acc[mi][ni][r] - mx));
                }
                if (l15 == 0)
                    part[((long long)bz * 2048 + rowg) * 32 + (bx << 1) +
                         (wave >> 1)] = make_float2(mx, sm);
            }
    } else {
#pragma unroll
        for (int mi = 0; mi < MI; ++mi)
#pragma unroll
            for (int ni = 0; ni < NI; ++ni) {
                int colg = n0 + wn + ni * 16 + l15;
                float bv = bias ? bias[colg] : 0.f;
#pragma unroll
                for (int r = 0; r < 4; ++r) {
                    int rowg = m0 + wm + mi * 16 + quad * 4 + r;
                    float v = acc[mi][ni][r] + bv;
                    int seg = colg >> 10;   // mode 2: segmented fp16
                    Ch[(long long)seg * sC + (long long)rowg * 1024 +
                       (colg & 1023)] = f2h(v);
                }
            }
    }
}

// plain GEMM kernel (proj): m157 XCD remap + body, mode 2
template <int TM, int TN>
__global__ __launch_bounds__(256, 2)
void gemm_nt(const unsigned short* __restrict__ A,
             const unsigned short* __restrict__ B,
             const float* __restrict__ bias,
             unsigned short* __restrict__ Ch,
             int mode, int N, int K,
             long long sA, long long sB, long long sC) {
    __shared__ unsigned short smem[(TM + TN) * BK];
    int bx, by, bz;
    xcd_remap(bx, by, bz);
    gemm_body<TM, TN>(smem, bx, by, bz, A, B, bias, Ch, nullptr, mode, N, K,
                      sA, sB, sC);
}

// ---------------------------------------------------------------------------
// scores + vT dispatch: 3072 blocks. Physical block f -> XCD c = f&7,
// rank = f>>3. rank<128: scores GEMM block 128x128 (XCD-chunked,
// w = c*128+rank over the (16,16,4) grid), mode 1 -> P~ fp16 + partials.
// rank>=128: one 64x64 v16->vT transpose tile (2048 tiles) backfilling.
// ---------------------------------------------------------------------------
__global__ __launch_bounds__(256, 2)
void scores_vT(const unsigned short* __restrict__ k16,
               const unsigned short* __restrict__ q16,
               unsigned short* __restrict__ P16,
               float2* __restrict__ part,
               const unsigned short* __restrict__ v,
               unsigned short* __restrict__ vT) {
    __shared__ unsigned short smem[(128 + 128) * BK];   // 32KB
    const int f = blockIdx.x;
    const int c = f & 7;
    const int rank = f >> 3;
    if (rank < 128) {
        const int w = c * 128 + rank;          // scores work id, XCD-chunked
        const int bx = w & 15;
        const int by = (w >> 4) & 15;
        const int bz = w >> 8;
        gemm_body<128, 128>(smem, bx, by, bz, k16, q16, nullptr, P16, part,
                            1, 2048, 1024,
                            (long long)2048 * 1024, (long long)2048 * 1024,
                            (long long)2048 * 2048);
    } else {
        // 64x64 transpose tile: t in [0,2048); 512 tiles per batch
        const int t = c * 256 + (rank - 128);
        auto tile = (unsigned short(*)[78])smem;   // 64x78 ushort = 9984B
        const int tid = threadIdx.x;
        int z = t >> 9;                  // batch
        int rest = t & 511;              // 16 a-tiles x 32 n-tiles
        int c0 = (rest & 15) * 64;       // a base
        int r0 = (rest >> 4) * 64;       // n base
        long long zs = (long long)z * 2048 * 1024;
        int tx = tid & 15, ty = tid >> 4;
#pragma unroll
        for (int j = 0; j < 4; ++j) {
            int r = ty + j * 16;
            ushort4 u = *(const ushort4*)(v + zs +
                                          (long long)(r0 + r) * 1024 + c0 + tx * 4);
            *(ushort4*)&tile[r][tx * 4] = u;
        }
        __syncthreads();
#pragma unroll
        for (int j = 0; j < 4; ++j) {
            int a = ty + j * 16;
            ushort4 u = make_ushort4(tile[tx * 4 + 0][a], tile[tx * 4 + 1][a],
                                     tile[tx * 4 + 2][a], tile[tx * 4 + 3][a]);
            *(ushort4*)(vT + zs + (long long)(c0 + a) * 2048 + r0 + tx * 4) = u;
        }
    }
}

// ---------------------------------------------------------------------------
// pv_fused (R19): out[b,n,a] = sum_t c'[n,t] * (P~_t @ vT_t)[n,a], where
// c' = fp16(exp(Mt - M)/S) already includes the softmax denominator.
// Block 128x64 (grid 16x16x4), 256 thr.  LDS = As 16K + Bs 8K + c16 8K
// = exactly 32KB -> 5 blocks/CU.  Both operands via gll16; per K-tile MFMA
// into zeroed tmp, then acc += c'_f32(row, tile) * tmp.  Epilogue: out=acc.
// ---------------------------------------------------------------------------
__global__ __launch_bounds__(256, 2)
void pv_fused(const unsigned short* __restrict__ P16,  // [4][2048][2048]
              const float2* __restrict__ part,          // [4][2048][32]
              const unsigned short* __restrict__ vT,    // [4][1024][2048]
              float* __restrict__ out) {                 // [4][2048][1024]
    constexpr int TM = 128, TN = 64, MI = 4, NI = 2, K = 2048;
    __shared__ unsigned short As[TM * BK];      // 16 KB
    __shared__ unsigned short Bs[TN * BK];      // 8 KB
    __shared__ unsigned short c16[TM][32];      // 8 KB  (c' = c/S)

    const int tid = threadIdx.x;
    const int lane = tid & 63;
    const int wave = tid >> 6;
    const int quad = lane >> 4;
    const int l15 = lane & 15;
    const int wm = (wave & 1) * 64;
    const int wn = (wave >> 1) * 32;

    int bx, by, bz;
    xcd_remap(bx, by, bz);                      // grid (16,16,4)
    const int m0 = by * TM;                     // n-row base
    const int n0 = bx * TN;                     // a-col base

    // ---- combine partials: thread pair (2 per row) over 16 slices each ----
    {
        const int row = tid >> 1;
        const int h = tid & 1;
        const float2* pp =
            part + ((long long)bz * 2048 + m0 + row) * 32 + h * 16;
        float pm[16], ps[16];
#pragma unroll
        for (int i = 0; i < 4; ++i) {
            float4 a = *(const float4*)(pp + i * 4);
            float4 b = *(const float4*)(pp + i * 4 + 2);
            pm[i * 4 + 0] = a.x; ps[i * 4 + 0] = a.y;
            pm[i * 4 + 1] = a.z; ps[i * 4 + 1] = a.w;
            pm[i * 4 + 2] = b.x; ps[i * 4 + 2] = b.y;
            pm[i * 4 + 3] = b.z; ps[i * 4 + 3] = b.w;
        }
        float m = pm[0];
#pragma unroll
        for (int i = 1; i < 16; ++i) m = fmaxf(m, pm[i]);
        float M = fmaxf(m, __shfl_xor(m, 1));   // pair = same row
        float s = 0.f;
#pragma unroll
        for (int i = 0; i < 16; ++i) s += ps[i] * __expf(pm[i] - M);
        s += __shfl_xor(s, 1);
        float inv = 1.0f / s;
#pragma unroll
        for (int i = 0; i < 16; ++i)
            c16[row][h * 16 + i] = f2h(__expf(pm[i] - M) * inv);
    }

    // staging geometry — identical to gemm_body (A=P~, B=vT, both K=2048)
    const int arow = wave * 32 + (lane >> 3);            // TM/4 = 32
    const int brow = wave * 16 + (lane >> 3);            // TN/4 = 16
    const int schunk8 = (((lane & 7) ^ ((lane >> 3) & 7)) << 3);
    const long long aoff =
        ((long long)bz * 2048 + m0 + arow) * 2048 + schunk8;
    const long long boff =
        ((long long)bz * 1024 + n0 + brow) * 2048 + schunk8;
    unsigned short* lA = As + (wave * 32) * BK;
    unsigned short* lB = Bs + (wave * 16) * BK;

    floatx4 zero = {0.f, 0.f, 0.f, 0.f};
    floatx4 acc[MI][NI];
#pragma unroll
    for (int i = 0; i < MI; ++i)
#pragma unroll
        for (int j = 0; j < NI; ++j) acc[i][j] = zero;

    __syncthreads();   // c16 visible (distinct LDS from As/Bs)

    for (int k0 = 0; k0 < K; k0 += BK) {
#pragma unroll
        for (int j = 0; j < 4; ++j)
            gll16(P16 + aoff + k0 + (long long)j * 8 * 2048, lA + j * 8 * BK);
#pragma unroll
        for (int j = 0; j < 2; ++j)
            gll16(vT + boff + k0 + (long long)j * 8 * 2048, lB + j * 8 * BK);
        __syncthreads();

        floatx4 tmp[MI][NI];
#pragma unroll
        for (int i = 0; i < MI; ++i)
#pragma unroll
            for (int j = 0; j < NI; ++j) tmp[i][j] = zero;

#pragma unroll
        for (int t = 0; t < 2; ++t) {
            half8 a[MI], b[NI];
#pragma unroll
            for (int mi = 0; mi < MI; ++mi) {
                int r = wm + mi * 16 + l15;
                int p = (t * 4 + quad) ^ (r & 7);
                a[mi] = *(const half8*)&As[r * BK + p * 8];
            }
#pragma unroll
            for (int ni = 0; ni < NI; ++ni) {
                int r = wn + ni * 16 + l15;
                int p = (t * 4 + quad) ^ (r & 7);
                b[ni] = *(const half8*)&Bs[r * BK + p * 8];
            }
#pragma unroll
            for (int mi = 0; mi < MI; ++mi)
#pragma unroll
                for (int ni = 0; ni < NI; ++ni)
                    tmp[mi][ni] = MFMA16(a[mi], b[ni], tmp[mi][ni], 0, 0, 0);
        }

        // fold normalized slice scale in fp32: acc += c'(row, slice) * tmp
        const int jt = k0 >> 6;
#pragma unroll
        for (int mi = 0; mi < MI; ++mi)
#pragma unroll
            for (int r = 0; r < 4; ++r) {
                float cf = h2f(c16[wm + mi * 16 + quad * 4 + r][jt]);
#pragma unroll
                for (int ni = 0; ni < NI; ++ni)
                    acc[mi][ni][r] += cf * tmp[mi][ni][r];
            }
        __syncthreads();
    }

    // epilogue: out = acc (c' already includes 1/S)
#pragma unroll
    for (int mi = 0; mi < MI; ++mi)
#pragma unroll
        for (int ni = 0; ni < NI; ++ni) {
            int colg = n0 + wn + ni * 16 + l15;
#pragma unroll
            for (int r = 0; r < 4; ++r) {
                int rowl = wm + mi * 16 + quad * 4 + r;
                out[((long long)bz * 2048 + m0 + rowl) * 1024 + colg] =
                    acc[mi][ni][r];
            }
        }
}

// ---------------------------------------------------------------------------
extern "C" void kernel_launch(void* const* d_in, const int* in_sizes, int n_in,
                              void* d_out, int out_size, void* d_ws,
                              size_t ws_size, hipStream_t stream) {
    const float* x  = (const float*)d_in[0];
    const float* Wk = (const float*)d_in[1];
    const float* bk = (const float*)d_in[2];
    const float* Wq = (const float*)d_in[3];
    const float* bq = (const float*)d_in[4];
    const float* Wv = (const float*)d_in[5];
    const float* bv = (const float*)d_in[6];
    float* out = (float*)d_out;

    const int Bb = 4, Ns = 2048, E = 1024, Aa = 1024;
    const int M = Bb * Ns;  // 8192

    char* p = (char*)d_ws;
    auto alloc = [&](size_t bytes) {
        char* r = p;
        p += (bytes + 255) & ~(size_t)255;
        return r;
    };
    const size_t MA = (size_t)M * Aa;          // 8.39M elems
    unsigned short* x16 = (unsigned short*)alloc(MA * 2);
    unsigned short* WT  = (unsigned short*)alloc((size_t)3 * E * Aa * 2);
    // k16,q16,v16 MUST be contiguous (segmented epilogue): MA*2 is a
    // multiple of 256, so alloc() inserts no padding.
    unsigned short* k16 = (unsigned short*)alloc(MA * 2);
    unsigned short* q16 = (unsigned short*)alloc(MA * 2);
    unsigned short* v16 = (unsigned short*)alloc(MA * 2);
    unsigned short* vT  = (unsigned short*)alloc(MA * 2);
    unsigned short* p16 = (unsigned short*)alloc((size_t)M * Ns * 2);
    float2* part = (float2*)alloc((size_t)M * 32 * 8);
    float* bias3 = (float*)alloc(3072 * 4);

    // 1. prep: x->fp16, W^T x3 (64x64 tiles), bias concat
    prep<<<8972, 256, 0, stream>>>(x, Wk, Wq, Wv, bk, bq, bv, x16, WT, bias3);

    // 2. fused projections: [k|q|v] = x16 @ [Wk|Wq|Wv]^T + bias3  (1536 blk)
    gemm_nt<128, 128><<<dim3(3 * Aa / 128, M / 128, 1), 256, 0, stream>>>(
        x16, WT, bias3, k16, 2, 3 * Aa, E, 0, 0, (long long)MA);

    // 3. scores (1024 XCD-chunked 128x128 blocks, mode 1 -> P~ + partials)
    //    + v->vT (2048 64x64 backfill tiles)
    scores_vT<<<3072, 256, 0, stream>>>(k16, q16, p16, part, v16, vT);

    // 4. pv_fused: combine partials + per-tile accumulator rescale (1024 blk)
    pv_fused<<<dim3(16, 16, 4), 256, 0, stream>>>(p16, part, vT, out);
}